// Round 9
// baseline (81.089 us; speedup 1.0000x reference)
//
#include <hip/hip_runtime.h>

// Problem constants (fixed by the reference's setup_inputs):
//   B=8, M=8192, D=256, MAX_HOP=3; all f32.
#define B 8
#define M 8192
#define D 256
#define BM (B * M)            // 65536 rows
#define BMD ((size_t)B * M * D)
#define HBLK 2048             // hop-kernel blocks; each owns 32 consecutive rows
#define RPB 32                // rows per block
#define RPW 8                 // rows per wave (4 waves/block)

// ---------------- init: zero the o~ accumulators (1 block) -----------------
__global__ __launch_bounds__(256) void init_kernel(float* __restrict__ on0,
                                                   float* __restrict__ on1) {
    const int t = threadIdx.x;
    #pragma unroll
    for (int i = 0; i < 8; ++i) { on0[i * 256 + t] = 0.f; on1[i * 256 + t] = 0.f; }
}

// ---------------- fused hop kernel (dual-stream register prefetch) ---------
// Per block (32 rows of batch b):
//   prologue: u_eff = query + on0/z0 (+ on1/z1)   (deferred softmax norm)
//   prefetch: BOTH st_o and st_dot row fragments into registers (overlapped
//             64 MB + 64 MB streams; 16 KB/wave in flight)
//   dot:      l = gp*<st_dot[row], u_eff>; butterfly reduce leaves sum in all
//             lanes -> w kept per-lane in registers (no LDS, no barrier)
//   o:        on_out[b][d] += sum_row w[row]*ofr[row]  (atomic, from regs)
// No max-subtraction: |l| <~ 10, f32 exp safe (validated rounds 1-8).
__global__ __launch_bounds__(256) void hop_kernel(
    const float* __restrict__ st_dot,   // slice for logits
    const float* __restrict__ st_o,     // slice for o_k (null on final hop)
    const float* __restrict__ query,    // [B][D]
    const float* __restrict__ gp,       // [B][M]
    const float* __restrict__ on0_in, const float* __restrict__ psum0,
    const float* __restrict__ on1_in, const float* __restrict__ psum1,
    float* __restrict__ on_out,         // [B][D] atomic accumulator (zeroed)
    float* __restrict__ psum_out,       // [HBLK]
    float* __restrict__ logits_out)     // final hop only
{
    const int bid = blockIdx.x;
    const int b = bid >> 8;                      // 256 blocks per batch
    const int tid = threadIdx.x, lane = tid & 63, wv = tid >> 6;
    const long long grow0 = (long long)bid * RPB;

    __shared__ float uu[256];
    __shared__ float gpv[RPB];
    __shared__ float sred[4];
    __shared__ float sacc[4][256];

    auto wave_red = [&](float v) -> float {
        #pragma unroll
        for (int off = 32; off; off >>= 1) v += __shfl_xor(v, off, 64);
        return v;
    };
    // z of a previous hop: sum that hop's 256 per-block partials (L2-hot)
    auto zsum = [&](const float* ps) -> float {
        float v = wave_red(ps[(b << 8) + tid]);
        if (lane == 0) sred[wv] = v;
        __syncthreads();
        const float z = sred[0] + sred[1] + sred[2] + sred[3];
        __syncthreads();
        return z;
    };

    // u_eff with deferred normalization folds (uniform branches: kernel args)
    float ueff = query[(b << 8) + tid];
    if (on0_in) ueff += on0_in[(b << 8) + tid] / zsum(psum0);
    if (on1_in) ueff += on1_in[(b << 8) + tid] / zsum(psum1);
    uu[tid] = ueff;
    if (tid < RPB) gpv[tid] = gp[grow0 + tid];
    __syncthreads();

    const float4 uf = reinterpret_cast<const float4*>(uu)[lane];

    // ---- issue BOTH streams' loads before any reduction ----
    float4 ofr[RPW];                 // o-phase fragments (32 VGPR)
    if (st_o != nullptr) {
        const float4* o4 = reinterpret_cast<const float4*>(st_o + grow0 * D) + lane;
        #pragma unroll
        for (int r = 0; r < RPW; ++r)
            ofr[r] = o4[(size_t)(wv * RPW + r) * 64];
    }
    float4 dfr[RPW];                 // dot-phase fragments (32 VGPR)
    {
        const float4* s4 = reinterpret_cast<const float4*>(st_dot + grow0 * D) + lane;
        #pragma unroll
        for (int r = 0; r < RPW; ++r)
            dfr[r] = s4[(size_t)(wv * RPW + r) * 64];
    }

    // ---- dot phase: w stays in registers (reduce result is in all lanes) --
    float ww[RPW];
    float esum = 0.f;
    #pragma unroll
    for (int r = 0; r < RPW; ++r) {
        const int lr = wv * RPW + r;
        float v = wave_red(dfr[r].x * uf.x + dfr[r].y * uf.y +
                           dfr[r].z * uf.z + dfr[r].w * uf.w);
        const float g = gpv[lr];
        const float l = v * g;
        const float e = __expf(l);
        esum += e;
        ww[r] = e * g;
        if (logits_out != nullptr && lane == 0) logits_out[grow0 + lr] = l;
    }
    if (lane == 0) sred[wv] = esum;
    __syncthreads();
    if (tid == 0) psum_out[bid] = sred[0] + sred[1] + sred[2] + sred[3];

    if (st_o == nullptr) return;     // final hop: dot only

    // ---- o phase: pure register math + one cross-wave LDS reduce ----
    float4 oacc = {0.f, 0.f, 0.f, 0.f};
    #pragma unroll
    for (int r = 0; r < RPW; ++r) {
        oacc.x += ww[r] * ofr[r].x; oacc.y += ww[r] * ofr[r].y;
        oacc.z += ww[r] * ofr[r].z; oacc.w += ww[r] * ofr[r].w;
    }
    reinterpret_cast<float4*>(&sacc[wv][0])[lane] = oacc;
    __syncthreads();
    atomicAdd(&on_out[(b << 8) + tid],
              sacc[0][tid] + sacc[1][tid] + sacc[2][tid] + sacc[3][tid]);
}

// ---------------- final prob_soft ------------------------------------------
__global__ __launch_bounds__(256) void prob_kernel(
    const float* __restrict__ logits,   // [B][M]
    const float* __restrict__ psum2,    // [HBLK]
    float* __restrict__ prob)           // [B][M]
{
    const int tid = threadIdx.x, lane = tid & 63, wv = tid >> 6;
    const int b = blockIdx.x >> 5;      // 32 blocks per batch
    __shared__ float sred[4];
    float v = psum2[(b << 8) + tid];
    #pragma unroll
    for (int off = 32; off; off >>= 1) v += __shfl_xor(v, off, 64);
    if (lane == 0) sred[wv] = v;
    __syncthreads();
    const float z = sred[0] + sred[1] + sred[2] + sred[3];
    const int i = blockIdx.x * 256 + tid;
    prob[i] = __expf(logits[i]) / z;
}

extern "C" void kernel_launch(void* const* d_in, const int* in_sizes, int n_in,
                              void* d_out, int out_size, void* d_ws, size_t ws_size,
                              hipStream_t stream) {
    const float* query = (const float*)d_in[0];   // [B][D]
    const float* gp    = (const float*)d_in[1];   // [B][M]
    const float* story = (const float*)d_in[2];   // [4][B][M][D]

    float* out    = (float*)d_out;
    float* prob   = out;             // [B][M] (output 0)
    float* logits = out + BM;        // [B][M] (output 1)

    float* ws    = (float*)d_ws;
    float* on0   = ws;               // 2048
    float* on1   = ws + 2048;        // 2048
    float* psum0 = ws + 4096;        // 2048
    float* psum1 = ws + 6144;        // 2048
    float* psum2 = ws + 8192;        // 2048

    const float* st0 = story;
    const float* st1 = story + BMD;
    const float* st2 = story + 2 * BMD;

    init_kernel<<<1, 256, 0, stream>>>(on0, on1);

    // H0: logits(st0, q) + o~0 over st1
    hop_kernel<<<HBLK, 256, 0, stream>>>(st0, st1, query, gp,
                                         nullptr, nullptr, nullptr, nullptr,
                                         on0, psum0, nullptr);
    // H1: logits(st1, q + o~0/z0) + o~1 over st2
    hop_kernel<<<HBLK, 256, 0, stream>>>(st1, st2, query, gp,
                                         on0, psum0, nullptr, nullptr,
                                         on1, psum1, nullptr);
    // H2: logits(st2, q + o~0/z0 + o~1/z1) -> logits out + psum2
    hop_kernel<<<HBLK, 256, 0, stream>>>(st2, nullptr, query, gp,
                                         on0, psum0, on1, psum1,
                                         nullptr, psum2, logits);
    prob_kernel<<<BM / 256, 256, 0, stream>>>(logits, psum2, prob);
}